// Round 14
// baseline (224.675 us; speedup 1.0000x reference)
//
#include <hip/hip_runtime.h>
#include <math.h>

typedef __attribute__((ext_vector_type(8))) short s16x8;   // 8 bf16 (4 VGPRs)
typedef __attribute__((ext_vector_type(4))) float f32x4;   // MFMA C/D

// Problem constants
#define B_    4
#define C_    64
#define S_    32768          // 32*32*32 spatial
#define N_    131072         // B_*S_ tokens
#define K_    512            // codebook size
#define SPLITS 8             // tasks per code in dw phase
#define DECAY_ 0.99f
#define ONEM_  0.01f
#define ALPHA_ 1e-5f
#define DELTA_ 0.01f         // margin >> split-emulation worst-case (~2.2e-3)
#define AMB_CAP 65536

// d_out layout (float32, concatenated in reference return order)
#define OFF_LOSS 0
#define OFF_Q    1
#define OFF_PERP 8388609
#define OFF_IDX  8388610
#define OFF_NEMB 8519682
#define OFF_NCS  8552450
#define OFF_NEA  8552962

// ws layout in 4-byte units
#define WS_LOSS   0
#define WS_AMBN   8
#define WS_CNT    16
#define WS_CUR    528
#define WS_OFFS   1040
#define WS_E2     2064
#define WS_SORT   2576
#define WS_PART   133648
#define WS_SPL    395792    // table2: [ct][split][kt][lane][e] ushorts, 128 KB
#define WS_AMB    444944
#define WS_ET     510480

__device__ __forceinline__ ushort f2bf(float f) {           // RNE fp32 -> bf16
    uint u = __float_as_uint(f);
    u = u + 0x7FFFu + ((u >> 16) & 1u);
    return (ushort)(u >> 16);
}
__device__ __forceinline__ float bf2f(ushort h) {
    return __uint_as_float(((uint)h) << 16);
}

// ---------------------------------------------------------------------------
// K0: split table in LANE-MAJOR layout: ushort idx =
//     ct*2048 + split*1024 + kt*512 + (q*16+col)*8 + e, so the consuming
//     lane's 16B fragment is contiguous -> conflict-free ds_read_b128 in
//     k_assign. Also ||e||^2, embed^T, counter zeroing.
// ---------------------------------------------------------------------------
__global__ __launch_bounds__(256) void k_split(const float* __restrict__ embed,
                                               float* __restrict__ wsf,
                                               int* __restrict__ wsi) {
    const int t = threadIdx.x;
    const int lane = t & 63;                     // = channel
    const int code = blockIdx.x * 4 + (t >> 6);
    if (blockIdx.x == 0) {
        for (int i = t; i < WS_OFFS; i += 256) wsi[i] = 0;   // LOSS/AMBN/CNT/CUR
    }
    const float e = embed[code * C_ + lane];
    const float sc = -2.f * e;
    const ushort h1 = f2bf(sc);
    const ushort h2 = f2bf(sc - bf2f(h1));
    ushort* tab2 = (ushort*)(wsf + WS_SPL);
    const int ct = code >> 4, col = code & 15;
    const int kt = lane >> 5, q = (lane >> 3) & 3, el = lane & 7;
    const int base2 = ct * 2048 + kt * 512 + (q * 16 + col) * 8 + el;
    tab2[base2] = h1;                            // split 0 (hi)
    tab2[base2 + 1024] = h2;                     // split 1 (lo)
    wsf[WS_ET + lane * K_ + code] = e;           // embed^T
    float sq = e * e;
    for (int o = 32; o > 0; o >>= 1) sq += __shfl_down(sq, o, 64);
    if (lane == 0) wsf[WS_E2 + code] = sq;
}

// ---------------------------------------------------------------------------
// K1: MFMA argmin. R23: DOUBLE-BUFFERED LDS staging — quarter q+1's global
//     loads issue into registers before quarter q's 8-ct MFMA block (L2
//     latency hidden under compute), ds_write after compute, ONE sync per
//     quarter (was 2). Math/order identical to the proven R22 body.
// ---------------------------------------------------------------------------
__global__ __launch_bounds__(256) void k_assign(const float* __restrict__ in,
                                                float* __restrict__ out,
                                                float* __restrict__ wsf,
                                                int* __restrict__ wsi) {
    __shared__ ushort s_tab[2][16384];           // 2 x 32 KB quarter buffers
    __shared__ float s_e2l[K_];
    __shared__ int   s_cnt[K_];
    __shared__ float s_x2[256];
    __shared__ float s_loss;

    const int t = threadIdx.x;
    const int lane = t & 63;
    const int w = t >> 6;
    const int col = lane & 15;
    const int quad = lane >> 4;

    for (int i = t; i < K_; i += 256) { s_e2l[i] = wsf[WS_E2 + i]; s_cnt[i] = 0; }
    if (t == 0) s_loss = 0.f;

    const int nw = blockIdx.x * 256 + w * 64;   // wave token base (64 tokens)

    s16x8 a[4][2][2];
#pragma unroll
    for (int j = 0; j < 4; ++j) {
        const int n = nw + j * 16 + col;
        const int base = ((n >> 15) << 21) + (n & (S_ - 1));
        float x0[8], x1[8];
#pragma unroll
        for (int q = 0; q < 8; ++q) {
            x0[q] = in[base + ((quad * 8 + q) << 15)];
            x1[q] = in[base + ((32 + quad * 8 + q) << 15)];
        }
        float x2 = 0.f;
#pragma unroll
        for (int q = 0; q < 8; ++q) x2 += x0[q] * x0[q] + x1[q] * x1[q];
        x2 += __shfl_xor(x2, 16, 64);
        x2 += __shfl_xor(x2, 32, 64);
        if (quad == 0) s_x2[w * 64 + j * 16 + col] = x2;

        float4* q0 = (float4*)(out + OFF_Q + (size_t)n * C_ + quad * 8);
        q0[0] = make_float4(x0[0], x0[1], x0[2], x0[3]);
        q0[1] = make_float4(x0[4], x0[5], x0[6], x0[7]);
        float4* q1 = (float4*)(out + OFF_Q + (size_t)n * C_ + 32 + quad * 8);
        q1[0] = make_float4(x1[0], x1[1], x1[2], x1[3]);
        q1[1] = make_float4(x1[4], x1[5], x1[6], x1[7]);

#pragma unroll
        for (int q = 0; q < 8; ++q) {
            ushort h = f2bf(x0[q]); a[j][0][0][q] = (short)h;
            a[j][1][0][q] = (short)f2bf(x0[q] - bf2f(h));
            h = f2bf(x1[q]); a[j][0][1][q] = (short)h;
            a[j][1][1][q] = (short)f2bf(x1[q] - bf2f(h));
        }
    }

    const ushort* gtab = (const ushort*)(wsf + WS_SPL);
    float bestd[4][4], bestd2[4][4];
    int   besti[4][4];
#pragma unroll
    for (int j = 0; j < 4; ++j)
#pragma unroll
        for (int r = 0; r < 4; ++r) { bestd[j][r] = 3.4e38f; bestd2[j][r] = 3.4e38f; besti[j][r] = 0; }

    // initial stage: quarter 0 -> buf 0 (also fences s_e2l/s_x2/s_cnt init)
#pragma unroll
    for (int it = 0; it < 8; ++it) {
        const int idx = (it * 256 + t) * 8;      // ushort index, 16B-aligned
        *(uint4*)&s_tab[0][idx] = *(const uint4*)&gtab[idx];
    }
    __syncthreads();

    for (int qh = 0; qh < 4; ++qh) {
        // issue next quarter's global loads early (latency hidden by MFMAs)
        uint4 pre[8];
        if (qh < 3) {
#pragma unroll
            for (int it = 0; it < 8; ++it) {
                const int idx = (it * 256 + t) * 8;
                pre[it] = *(const uint4*)&gtab[(qh + 1) * 16384 + idx];
            }
        }

        const s16x8* ltab = (const s16x8*)s_tab[qh & 1];
        int lo = lane;                           // frag idx: ctQ*256 + s*128 + kt*64 + lane
        s16x8 bh0 = ltab[lo],       bh1 = ltab[lo + 64];
        s16x8 bl0 = ltab[lo + 128], bl1 = ltab[lo + 192];

        for (int cc = 0; cc < 8; ++cc) {
            const int ct = qh * 8 + cc;
            s16x8 nh0, nh1, nl0, nl1;
            if (cc < 7) {
                const int on = lo + 256;
                nh0 = ltab[on];       nh1 = ltab[on + 64];
                nl0 = ltab[on + 128]; nl1 = ltab[on + 192];
            }
            const float e2c = s_e2l[ct * 16 + col];
            f32x4 acc[4];
#pragma unroll
            for (int j = 0; j < 4; ++j) acc[j] = (f32x4){e2c, e2c, e2c, e2c};
            // term-major, smallest first; lo*lo dropped; 4 independent chains
#pragma unroll
            for (int j = 0; j < 4; ++j) acc[j] = __builtin_amdgcn_mfma_f32_16x16x32_bf16(a[j][1][0], bh0, acc[j], 0, 0, 0);
#pragma unroll
            for (int j = 0; j < 4; ++j) acc[j] = __builtin_amdgcn_mfma_f32_16x16x32_bf16(a[j][1][1], bh1, acc[j], 0, 0, 0);
#pragma unroll
            for (int j = 0; j < 4; ++j) acc[j] = __builtin_amdgcn_mfma_f32_16x16x32_bf16(a[j][0][0], bl0, acc[j], 0, 0, 0);
#pragma unroll
            for (int j = 0; j < 4; ++j) acc[j] = __builtin_amdgcn_mfma_f32_16x16x32_bf16(a[j][0][1], bl1, acc[j], 0, 0, 0);
#pragma unroll
            for (int j = 0; j < 4; ++j) acc[j] = __builtin_amdgcn_mfma_f32_16x16x32_bf16(a[j][0][0], bh0, acc[j], 0, 0, 0);
#pragma unroll
            for (int j = 0; j < 4; ++j) acc[j] = __builtin_amdgcn_mfma_f32_16x16x32_bf16(a[j][0][1], bh1, acc[j], 0, 0, 0);

            const int code = ct * 16 + col;
#pragma unroll
            for (int j = 0; j < 4; ++j) {
#pragma unroll
                for (int r = 0; r < 4; ++r) {
                    const float av = acc[j][r];
                    bestd2[j][r] = fminf(bestd2[j][r], fmaxf(av, bestd[j][r]));
                    if (av < bestd[j][r]) { bestd[j][r] = av; besti[j][r] = code; }
                }
            }
            bh0 = nh0; bh1 = nh1; bl0 = nl0; bl1 = nl1;
            lo += 256;
        }

        // write next quarter into the other buffer (consumed-quarter data
        // there was fully read before the previous sync)
        if (qh < 3) {
#pragma unroll
            for (int it = 0; it < 8; ++it) {
                const int idx = (it * 256 + t) * 8;
                *(uint4*)&s_tab[(qh + 1) & 1][idx] = pre[it];
            }
        }
        __syncthreads();
    }

    float lsum = 0.f;
#pragma unroll
    for (int j = 0; j < 4; ++j) {
#pragma unroll
        for (int r = 0; r < 4; ++r) {
            float d1 = bestd[j][r], d2 = bestd2[j][r]; int i1 = besti[j][r];
            for (int m = 1; m <= 8; m <<= 1) {
                const float d1o = __shfl_xor(d1, m, 64);
                const int   i1o = __shfl_xor(i1, m, 64);
                const float d2o = __shfl_xor(d2, m, 64);
                if (d1o < d1 || (d1o == d1 && i1o < i1)) {
                    d2 = fminf(d1, d2o); d1 = d1o; i1 = i1o;
                } else {
                    d2 = fminf(d2, d1o);
                }
            }
            if (col == 0) {
                const int tok = j * 16 + quad * 4 + r;
                out[OFF_IDX + nw + tok] = (float)i1;
                atomicAdd(&s_cnt[i1], 1);
                lsum += d1 + s_x2[w * 64 + tok];
                if (d2 - d1 < DELTA_) {
                    const int pos = atomicAdd(&wsi[WS_AMBN], 1);
                    if (pos < AMB_CAP) wsi[WS_AMB + pos] = nw + tok;
                }
            }
        }
    }
    if (col == 0) atomicAdd(&s_loss, lsum);
    __syncthreads();
    for (int i = t; i < K_; i += 256) {
        const int v = s_cnt[i];
        if (v) atomicAdd(&wsi[WS_CNT + i], v);
    }
    if (t == 0) atomicAdd(&wsf[WS_LOSS], s_loss);
}

// ---------------------------------------------------------------------------
// K1b: exact fp32 rescore of ambiguous tokens — R16 body verbatim (proven).
// ---------------------------------------------------------------------------
__global__ __launch_bounds__(256) void k_fixup(float* __restrict__ out,
                                               const float* __restrict__ wsf,
                                               int* __restrict__ wsi) {
    __shared__ float sx[4][C_];
    const int t = threadIdx.x;
    const int lane = t & 63;
    const int w = t >> 6;
    const int gw = blockIdx.x * 4 + w;
    const int nw = gridDim.x * 4;
    int cntA = wsi[WS_AMBN];
    if (cntA > AMB_CAP) cntA = AMB_CAP;
    const float* eT = wsf + WS_ET;

    for (int a = gw; a < cntA; a += nw) {
        const int n = wsi[WS_AMB + a];
        const float xv = out[OFF_Q + (size_t)n * C_ + lane];
        sx[w][lane] = xv;
        float x2 = xv * xv;
        for (int m = 1; m <= 32; m <<= 1) x2 += __shfl_xor(x2, m, 64);

        float bd = 3.4e38f; int bi = 0;
#pragma unroll 2
        for (int q = 0; q < 8; ++q) {
            const int k = (q << 6) + lane;
            float d0 = 0.f, d1 = 0.f, d2 = 0.f, d3 = 0.f;
#pragma unroll
            for (int c = 0; c < C_; c += 4) {
                d0 += sx[w][c + 0] * eT[(c + 0) * K_ + k];
                d1 += sx[w][c + 1] * eT[(c + 1) * K_ + k];
                d2 += sx[w][c + 2] * eT[(c + 2) * K_ + k];
                d3 += sx[w][c + 3] * eT[(c + 3) * K_ + k];
            }
            const float dist = x2 + wsf[WS_E2 + k] - 2.f * ((d0 + d1) + (d2 + d3));
            if (dist < bd) { bd = dist; bi = k; }
        }
        for (int m = 1; m <= 32; m <<= 1) {
            const float db = __shfl_xor(bd, m, 64);
            const int   ib = __shfl_xor(bi, m, 64);
            if (db < bd || (db == bd && ib < bi)) { bd = db; bi = ib; }
        }
        if (lane == 0) {
            const int old = (int)out[OFF_IDX + n];
            if (bi != old) {
                out[OFF_IDX + n] = (float)bi;
                atomicAdd(&wsi[WS_CNT + old], -1);
                atomicAdd(&wsi[WS_CNT + bi], 1);
            }
        }
    }
}

// ---------------------------------------------------------------------------
// K3: counting-sort scatter with redundant per-block prefix scan (block 0
//     publishes WS_OFFS). SCT=1024, 128 blocks — R9-proven config.
// ---------------------------------------------------------------------------
#define SCT 1024
__global__ __launch_bounds__(256) void k_scatter(const float* __restrict__ out,
                                                 int* __restrict__ wsi) {
    __shared__ int sA[K_];
    __shared__ int sB[K_];
    __shared__ int lc[K_];
    __shared__ int codes[SCT];
    const int t = threadIdx.x;
    const int base = blockIdx.x * SCT;

    const int c0 = wsi[WS_CNT + t];
    const int c1 = wsi[WS_CNT + t + 256];
    sA[t] = c0; sA[t + 256] = c1;
    __syncthreads();
    int* sa = sA; int* sb = sB;
    for (int o = 1; o < K_; o <<= 1) {            // inclusive Hillis-Steele
        const int va = sa[t]       + ((t >= o)       ? sa[t - o]       : 0);
        const int vb = sa[t + 256] + ((t + 256 >= o) ? sa[t + 256 - o] : 0);
        sb[t] = va; sb[t + 256] = vb;
        __syncthreads();
        int* tmp = sa; sa = sb; sb = tmp;
    }
    const int offs0 = sa[t] - c0;                 // exclusive prefix
    const int offs1 = sa[t + 256] - c1;
    if (blockIdx.x == 0) { wsi[WS_OFFS + t] = offs0; wsi[WS_OFFS + t + 256] = offs1; }

    int* hist = sb;                               // free buffer after scan
    hist[t] = 0; hist[t + 256] = 0;
    lc[t] = 0;  lc[t + 256] = 0;
    __syncthreads();
#pragma unroll
    for (int j = 0; j < SCT / 256; ++j) {
        const int k = (int)out[OFF_IDX + base + j * 256 + t];
        codes[j * 256 + t] = k;
        atomicAdd(&hist[k], 1);
    }
    __syncthreads();
    const int ha = hist[t];
    const int hb = hist[t + 256];
    int ga = 0, gb = 0;
    if (ha > 0) ga = atomicAdd(&wsi[WS_CUR + t], ha);
    if (hb > 0) gb = atomicAdd(&wsi[WS_CUR + t + 256], hb);
    __syncthreads();
    hist[t] = offs0 + ga;                         // absolute base per code
    hist[t + 256] = offs1 + gb;
    __syncthreads();
#pragma unroll
    for (int j = 0; j < SCT / 256; ++j) {
        const int k = codes[j * 256 + t];
        const int pos = atomicAdd(&lc[k], 1);
        wsi[WS_SORT + hist[k] + pos] = base + j * 256 + t;
    }
}

// ---------------------------------------------------------------------------
// K4: dw partials (depth-8 gathers — R9-proven config).
// ---------------------------------------------------------------------------
__global__ __launch_bounds__(64) void k_dw_split(float* __restrict__ out,
                                                 float* __restrict__ wsf,
                                                 const int* __restrict__ wsi) {
    const int lane = threadIdx.x;
    const int k = blockIdx.x >> 3;
    const int p = blockIdx.x & (SPLITS - 1);
    const int off = wsi[WS_OFFS + k];
    const int cnt = wsi[WS_CNT + k];
    const int chunk = (cnt + SPLITS - 1) >> 3;
    const int j0 = p * chunk;
    const int j1 = min(j0 + chunk, cnt);
    const float* fx = out + OFF_Q;
    const int* sort = wsi + WS_SORT + off;

    float acc = 0.f;
    for (int base = j0; base < j1; base += 64) {
        const int mcnt = min(64, j1 - base);
        int id = 0;
        if (base + lane < j1) id = sort[base + lane];
        int m = 0;
        for (; m + 8 <= mcnt; m += 8) {
            const int t0 = __shfl(id, m + 0, 64);
            const int t1 = __shfl(id, m + 1, 64);
            const int t2 = __shfl(id, m + 2, 64);
            const int t3 = __shfl(id, m + 3, 64);
            const int t4 = __shfl(id, m + 4, 64);
            const int t5 = __shfl(id, m + 5, 64);
            const int t6 = __shfl(id, m + 6, 64);
            const int t7 = __shfl(id, m + 7, 64);
            const float v0 = fx[(size_t)t0 * C_ + lane];
            const float v1 = fx[(size_t)t1 * C_ + lane];
            const float v2 = fx[(size_t)t2 * C_ + lane];
            const float v3 = fx[(size_t)t3 * C_ + lane];
            const float v4 = fx[(size_t)t4 * C_ + lane];
            const float v5 = fx[(size_t)t5 * C_ + lane];
            const float v6 = fx[(size_t)t6 * C_ + lane];
            const float v7 = fx[(size_t)t7 * C_ + lane];
            acc += ((v0 + v1) + (v2 + v3)) + ((v4 + v5) + (v6 + v7));
        }
        for (; m < mcnt; ++m) {
            const int tk = __shfl(id, m, 64);
            acc += fx[(size_t)tk * C_ + lane];
        }
    }
    wsf[WS_PART + (size_t)blockIdx.x * C_ + lane] = acc;
}

// ---------------------------------------------------------------------------
// K5: fused stats + ema + quant (R9-proven config).
// ---------------------------------------------------------------------------
__global__ __launch_bounds__(256) void k_emaq(const float* __restrict__ embed,
                                              const float* __restrict__ embed_avg,
                                              const float* __restrict__ cs,
                                              float* __restrict__ out,
                                              const float* __restrict__ wsf,
                                              const int* __restrict__ wsi) {
    __shared__ float sn[256];
    __shared__ float sncs[K_];
    const int t = threadIdx.x;
    const int bid = blockIdx.x;

    const int c0 = wsi[WS_CNT + t];
    const int c1 = wsi[WS_CNT + t + 256];
    const float ncs0 = cs[t] * DECAY_ + ONEM_ * (float)c0;
    const float ncs1 = cs[t + 256] * DECAY_ + ONEM_ * (float)c1;
    sncs[t] = ncs0; sncs[t + 256] = ncs1;
    sn[t] = ncs0 + ncs1;
    __syncthreads();
    for (int o = 128; o > 0; o >>= 1) { if (t < o) sn[t] += sn[t + o]; __syncthreads(); }
    const float ntot = sn[0];
    __syncthreads();

    if (bid == 0) {
        out[OFF_NCS + t] = ncs0;
        out[OFF_NCS + t + 256] = ncs1;
        const float ap0 = (float)c0 / (float)N_;
        const float ap1 = (float)c1 / (float)N_;
        sn[t] = ap0 * logf(ap0 + 1e-10f) + ap1 * logf(ap1 + 1e-10f);
        __syncthreads();
        for (int o = 128; o > 0; o >>= 1) { if (t < o) sn[t] += sn[t + o]; __syncthreads(); }
        if (t == 0) {
            out[OFF_PERP] = expf(-sn[0]);
            out[OFF_LOSS] = 0.25f * wsf[WS_LOSS] / (float)((long long)N_ * C_);
        }
    }

    if (bid < 128) {
        const int i = bid * 256 + t;           // i = k*64 + c
        const int k = i >> 6;
        const int c = i & 63;
        const float smooth = ntot * (sncs[k] + ALPHA_) / (ntot + (float)K_ * ALPHA_);
        float dw = 0.f;
#pragma unroll
        for (int p = 0; p < SPLITS; ++p)
            dw += wsf[WS_PART + (size_t)(k * SPLITS + p) * C_ + c];
        const float nea = embed_avg[i] * DECAY_ + ONEM_ * dw;
        out[OFF_NEA + i] = nea;
        out[OFF_NEMB + i] = nea / smooth;
    }

    const int n = bid * 256 + t;
    const int b = n >> 15;
    const int s = n & (S_ - 1);
    const int qbase = (b << 21) + s;
    const int k = (int)out[OFF_IDX + n];
    const float4* er = (const float4*)(embed + k * C_);
#pragma unroll
    for (int q = 0; q < 16; ++q) {
        float4 v = er[q];
        out[OFF_Q + qbase + ((4 * q + 0) << 15)] = v.x;
        out[OFF_Q + qbase + ((4 * q + 1) << 15)] = v.y;
        out[OFF_Q + qbase + ((4 * q + 2) << 15)] = v.z;
        out[OFF_Q + qbase + ((4 * q + 3) << 15)] = v.w;
    }
}

extern "C" void kernel_launch(void* const* d_in, const int* in_sizes, int n_in,
                              void* d_out, int out_size, void* d_ws, size_t ws_size,
                              hipStream_t stream) {
    const float* in        = (const float*)d_in[0];
    const float* embed     = (const float*)d_in[1];
    const float* embed_avg = (const float*)d_in[2];
    const float* cs        = (const float*)d_in[3];
    float* out = (float*)d_out;
    float* wsf = (float*)d_ws;
    int*   wsi = (int*)d_ws;

    k_split   <<<K_ / 4, 256, 0, stream>>>(embed, wsf, wsi);
    k_assign  <<<N_ / 256, 256, 0, stream>>>(in, out, wsf, wsi);
    k_fixup   <<<256, 256, 0, stream>>>(out, wsf, wsi);
    k_scatter <<<N_ / SCT, 256, 0, stream>>>(out, wsi);
    k_dw_split<<<K_ * SPLITS, 64, 0, stream>>>(out, wsf, wsi);
    k_emaq    <<<N_ / 256, 256, 0, stream>>>(embed, embed_avg, cs, out, wsf, wsi);
}

// Round 15
// 196.613 us; speedup vs baseline: 1.1427x; 1.1427x over previous
//
#include <hip/hip_runtime.h>
#include <math.h>

typedef __attribute__((ext_vector_type(8))) short s16x8;   // 8 bf16 (4 VGPRs)
typedef __attribute__((ext_vector_type(4))) float f32x4;   // MFMA C/D

// Problem constants
#define B_    4
#define C_    64
#define S_    32768          // 32*32*32 spatial
#define N_    131072         // B_*S_ tokens
#define K_    512            // codebook size
#define SPLITS 8             // tasks per code in dw phase
#define DECAY_ 0.99f
#define ONEM_  0.01f
#define ALPHA_ 1e-5f
#define DELTA_ 0.01f         // margin >> split-emulation worst-case (~2.2e-3)
#define AMB_CAP 65536

// d_out layout (float32, concatenated in reference return order)
#define OFF_LOSS 0
#define OFF_Q    1
#define OFF_PERP 8388609
#define OFF_IDX  8388610
#define OFF_NEMB 8519682
#define OFF_NCS  8552450
#define OFF_NEA  8552962

// ws layout in 4-byte units
#define WS_LOSS   0
#define WS_AMBN   8
#define WS_CNT    16
#define WS_CUR    528
#define WS_OFFS   1040
#define WS_E2     2064
#define WS_SORT   2576
#define WS_PART   133648
#define WS_SPL    395792    // table2: [ct][split][kt][lane][e] ushorts, 128 KB
#define WS_AMB    444944
#define WS_ET     510480

__device__ __forceinline__ ushort f2bf(float f) {           // RNE fp32 -> bf16
    uint u = __float_as_uint(f);
    u = u + 0x7FFFu + ((u >> 16) & 1u);
    return (ushort)(u >> 16);
}
__device__ __forceinline__ float bf2f(ushort h) {
    return __uint_as_float(((uint)h) << 16);
}

// ---------------------------------------------------------------------------
// K0: split table in LANE-MAJOR layout (R22): ushort idx =
//     ct*2048 + split*1024 + kt*512 + (q*16+col)*8 + e, so the consuming
//     lane's 16B fragment is contiguous -> conflict-free ds_read_b128 in
//     k_assign. Also ||e||^2, embed^T, counter zeroing.
// ---------------------------------------------------------------------------
__global__ __launch_bounds__(256) void k_split(const float* __restrict__ embed,
                                               float* __restrict__ wsf,
                                               int* __restrict__ wsi) {
    const int t = threadIdx.x;
    const int lane = t & 63;                     // = channel
    const int code = blockIdx.x * 4 + (t >> 6);
    if (blockIdx.x == 0) {
        for (int i = t; i < WS_OFFS; i += 256) wsi[i] = 0;   // LOSS/AMBN/CNT/CUR
    }
    const float e = embed[code * C_ + lane];
    const float sc = -2.f * e;
    const ushort h1 = f2bf(sc);
    const ushort h2 = f2bf(sc - bf2f(h1));
    ushort* tab2 = (ushort*)(wsf + WS_SPL);
    const int ct = code >> 4, col = code & 15;
    const int kt = lane >> 5, q = (lane >> 3) & 3, el = lane & 7;
    const int base2 = ct * 2048 + kt * 512 + (q * 16 + col) * 8 + el;
    tab2[base2] = h1;                            // split 0 (hi)
    tab2[base2 + 1024] = h2;                     // split 1 (lo)
    wsf[WS_ET + lane * K_ + code] = e;           // embed^T
    float sq = e * e;
    for (int o = 32; o > 0; o >>= 1) sq += __shfl_down(sq, o, 64);
    if (lane == 0) wsf[WS_E2 + code] = sq;
}

// ---------------------------------------------------------------------------
// K1: MFMA argmin. R22 body (best measured: 199.1us total): B tiles served
//     from LDS — table staged in 4x32KB quarters (8 cts each), conflict-free
//     lane-consecutive ds_read_b128, 1-deep register prefetch. R23's
//     double-buffer variant regressed (VGPR 196, spills, occ 10%) — this
//     single-buffer form is the converged configuration; do not add state.
// ---------------------------------------------------------------------------
__global__ __launch_bounds__(256) void k_assign(const float* __restrict__ in,
                                                float* __restrict__ out,
                                                float* __restrict__ wsf,
                                                int* __restrict__ wsi) {
    __shared__ ushort s_tab[16384];              // 32 KB quarter buffer
    __shared__ float s_e2l[K_];
    __shared__ int   s_cnt[K_];
    __shared__ float s_x2[256];
    __shared__ float s_loss;

    const int t = threadIdx.x;
    const int lane = t & 63;
    const int w = t >> 6;
    const int col = lane & 15;
    const int quad = lane >> 4;

    for (int i = t; i < K_; i += 256) { s_e2l[i] = wsf[WS_E2 + i]; s_cnt[i] = 0; }
    if (t == 0) s_loss = 0.f;

    const int nw = blockIdx.x * 256 + w * 64;   // wave token base (64 tokens)

    s16x8 a[4][2][2];
#pragma unroll
    for (int j = 0; j < 4; ++j) {
        const int n = nw + j * 16 + col;
        const int base = ((n >> 15) << 21) + (n & (S_ - 1));
        float x0[8], x1[8];
#pragma unroll
        for (int q = 0; q < 8; ++q) {
            x0[q] = in[base + ((quad * 8 + q) << 15)];
            x1[q] = in[base + ((32 + quad * 8 + q) << 15)];
        }
        float x2 = 0.f;
#pragma unroll
        for (int q = 0; q < 8; ++q) x2 += x0[q] * x0[q] + x1[q] * x1[q];
        x2 += __shfl_xor(x2, 16, 64);
        x2 += __shfl_xor(x2, 32, 64);
        if (quad == 0) s_x2[w * 64 + j * 16 + col] = x2;

        float4* q0 = (float4*)(out + OFF_Q + (size_t)n * C_ + quad * 8);
        q0[0] = make_float4(x0[0], x0[1], x0[2], x0[3]);
        q0[1] = make_float4(x0[4], x0[5], x0[6], x0[7]);
        float4* q1 = (float4*)(out + OFF_Q + (size_t)n * C_ + 32 + quad * 8);
        q1[0] = make_float4(x1[0], x1[1], x1[2], x1[3]);
        q1[1] = make_float4(x1[4], x1[5], x1[6], x1[7]);

#pragma unroll
        for (int q = 0; q < 8; ++q) {
            ushort h = f2bf(x0[q]); a[j][0][0][q] = (short)h;
            a[j][1][0][q] = (short)f2bf(x0[q] - bf2f(h));
            h = f2bf(x1[q]); a[j][0][1][q] = (short)h;
            a[j][1][1][q] = (short)f2bf(x1[q] - bf2f(h));
        }
    }

    const ushort* gtab = (const ushort*)(wsf + WS_SPL);
    float bestd[4][4], bestd2[4][4];
    int   besti[4][4];
#pragma unroll
    for (int j = 0; j < 4; ++j)
#pragma unroll
        for (int r = 0; r < 4; ++r) { bestd[j][r] = 3.4e38f; bestd2[j][r] = 3.4e38f; besti[j][r] = 0; }

    for (int qh = 0; qh < 4; ++qh) {
        __syncthreads();                         // s_tab reuse + (qh==0) s_e2l/s_x2
        // stage 32 KB quarter: 8 x 256 threads x 16 B, linear copy
#pragma unroll
        for (int it = 0; it < 8; ++it) {
            const int idx = (it * 256 + t) * 8;  // ushort index, 16B-aligned
            *(uint4*)&s_tab[idx] = *(const uint4*)&gtab[qh * 16384 + idx];
        }
        __syncthreads();

        const s16x8* ltab = (const s16x8*)s_tab;
        int lo = lane;                           // s16x8 idx: ctQ*256 + s*128 + kt*64 + lane
        s16x8 bh0 = ltab[lo],       bh1 = ltab[lo + 64];
        s16x8 bl0 = ltab[lo + 128], bl1 = ltab[lo + 192];

        for (int cc = 0; cc < 8; ++cc) {
            const int ct = qh * 8 + cc;
            s16x8 nh0, nh1, nl0, nl1;
            if (cc < 7) {
                const int on = lo + 256;
                nh0 = ltab[on];       nh1 = ltab[on + 64];
                nl0 = ltab[on + 128]; nl1 = ltab[on + 192];
            }
            const float e2c = s_e2l[ct * 16 + col];
            f32x4 acc[4];
#pragma unroll
            for (int j = 0; j < 4; ++j) acc[j] = (f32x4){e2c, e2c, e2c, e2c};
            // term-major, smallest first; lo*lo dropped; 4 independent chains
#pragma unroll
            for (int j = 0; j < 4; ++j) acc[j] = __builtin_amdgcn_mfma_f32_16x16x32_bf16(a[j][1][0], bh0, acc[j], 0, 0, 0);
#pragma unroll
            for (int j = 0; j < 4; ++j) acc[j] = __builtin_amdgcn_mfma_f32_16x16x32_bf16(a[j][1][1], bh1, acc[j], 0, 0, 0);
#pragma unroll
            for (int j = 0; j < 4; ++j) acc[j] = __builtin_amdgcn_mfma_f32_16x16x32_bf16(a[j][0][0], bl0, acc[j], 0, 0, 0);
#pragma unroll
            for (int j = 0; j < 4; ++j) acc[j] = __builtin_amdgcn_mfma_f32_16x16x32_bf16(a[j][0][1], bl1, acc[j], 0, 0, 0);
#pragma unroll
            for (int j = 0; j < 4; ++j) acc[j] = __builtin_amdgcn_mfma_f32_16x16x32_bf16(a[j][0][0], bh0, acc[j], 0, 0, 0);
#pragma unroll
            for (int j = 0; j < 4; ++j) acc[j] = __builtin_amdgcn_mfma_f32_16x16x32_bf16(a[j][0][1], bh1, acc[j], 0, 0, 0);

            const int code = ct * 16 + col;
#pragma unroll
            for (int j = 0; j < 4; ++j) {
#pragma unroll
                for (int r = 0; r < 4; ++r) {
                    const float av = acc[j][r];
                    bestd2[j][r] = fminf(bestd2[j][r], fmaxf(av, bestd[j][r]));
                    if (av < bestd[j][r]) { bestd[j][r] = av; besti[j][r] = code; }
                }
            }
            bh0 = nh0; bh1 = nh1; bl0 = nl0; bl1 = nl1;
            lo += 256;
        }
    }

    float lsum = 0.f;
#pragma unroll
    for (int j = 0; j < 4; ++j) {
#pragma unroll
        for (int r = 0; r < 4; ++r) {
            float d1 = bestd[j][r], d2 = bestd2[j][r]; int i1 = besti[j][r];
            for (int m = 1; m <= 8; m <<= 1) {
                const float d1o = __shfl_xor(d1, m, 64);
                const int   i1o = __shfl_xor(i1, m, 64);
                const float d2o = __shfl_xor(d2, m, 64);
                if (d1o < d1 || (d1o == d1 && i1o < i1)) {
                    d2 = fminf(d1, d2o); d1 = d1o; i1 = i1o;
                } else {
                    d2 = fminf(d2, d1o);
                }
            }
            if (col == 0) {
                const int tok = j * 16 + quad * 4 + r;
                out[OFF_IDX + nw + tok] = (float)i1;
                atomicAdd(&s_cnt[i1], 1);
                lsum += d1 + s_x2[w * 64 + tok];
                if (d2 - d1 < DELTA_) {
                    const int pos = atomicAdd(&wsi[WS_AMBN], 1);
                    if (pos < AMB_CAP) wsi[WS_AMB + pos] = nw + tok;
                }
            }
        }
    }
    if (col == 0) atomicAdd(&s_loss, lsum);
    __syncthreads();
    for (int i = t; i < K_; i += 256) {
        const int v = s_cnt[i];
        if (v) atomicAdd(&wsi[WS_CNT + i], v);
    }
    if (t == 0) atomicAdd(&wsf[WS_LOSS], s_loss);
}

// ---------------------------------------------------------------------------
// K1b: exact fp32 rescore of ambiguous tokens — R16 body verbatim (proven).
// ---------------------------------------------------------------------------
__global__ __launch_bounds__(256) void k_fixup(float* __restrict__ out,
                                               const float* __restrict__ wsf,
                                               int* __restrict__ wsi) {
    __shared__ float sx[4][C_];
    const int t = threadIdx.x;
    const int lane = t & 63;
    const int w = t >> 6;
    const int gw = blockIdx.x * 4 + w;
    const int nw = gridDim.x * 4;
    int cntA = wsi[WS_AMBN];
    if (cntA > AMB_CAP) cntA = AMB_CAP;
    const float* eT = wsf + WS_ET;

    for (int a = gw; a < cntA; a += nw) {
        const int n = wsi[WS_AMB + a];
        const float xv = out[OFF_Q + (size_t)n * C_ + lane];
        sx[w][lane] = xv;
        float x2 = xv * xv;
        for (int m = 1; m <= 32; m <<= 1) x2 += __shfl_xor(x2, m, 64);

        float bd = 3.4e38f; int bi = 0;
#pragma unroll 2
        for (int q = 0; q < 8; ++q) {
            const int k = (q << 6) + lane;
            float d0 = 0.f, d1 = 0.f, d2 = 0.f, d3 = 0.f;
#pragma unroll
            for (int c = 0; c < C_; c += 4) {
                d0 += sx[w][c + 0] * eT[(c + 0) * K_ + k];
                d1 += sx[w][c + 1] * eT[(c + 1) * K_ + k];
                d2 += sx[w][c + 2] * eT[(c + 2) * K_ + k];
                d3 += sx[w][c + 3] * eT[(c + 3) * K_ + k];
            }
            const float dist = x2 + wsf[WS_E2 + k] - 2.f * ((d0 + d1) + (d2 + d3));
            if (dist < bd) { bd = dist; bi = k; }
        }
        for (int m = 1; m <= 32; m <<= 1) {
            const float db = __shfl_xor(bd, m, 64);
            const int   ib = __shfl_xor(bi, m, 64);
            if (db < bd || (db == bd && ib < bi)) { bd = db; bi = ib; }
        }
        if (lane == 0) {
            const int old = (int)out[OFF_IDX + n];
            if (bi != old) {
                out[OFF_IDX + n] = (float)bi;
                atomicAdd(&wsi[WS_CNT + old], -1);
                atomicAdd(&wsi[WS_CNT + bi], 1);
            }
        }
    }
}

// ---------------------------------------------------------------------------
// K3: counting-sort scatter with redundant per-block prefix scan (block 0
//     publishes WS_OFFS). SCT=1024, 128 blocks — R9-proven config.
// ---------------------------------------------------------------------------
#define SCT 1024
__global__ __launch_bounds__(256) void k_scatter(const float* __restrict__ out,
                                                 int* __restrict__ wsi) {
    __shared__ int sA[K_];
    __shared__ int sB[K_];
    __shared__ int lc[K_];
    __shared__ int codes[SCT];
    const int t = threadIdx.x;
    const int base = blockIdx.x * SCT;

    const int c0 = wsi[WS_CNT + t];
    const int c1 = wsi[WS_CNT + t + 256];
    sA[t] = c0; sA[t + 256] = c1;
    __syncthreads();
    int* sa = sA; int* sb = sB;
    for (int o = 1; o < K_; o <<= 1) {            // inclusive Hillis-Steele
        const int va = sa[t]       + ((t >= o)       ? sa[t - o]       : 0);
        const int vb = sa[t + 256] + ((t + 256 >= o) ? sa[t + 256 - o] : 0);
        sb[t] = va; sb[t + 256] = vb;
        __syncthreads();
        int* tmp = sa; sa = sb; sb = tmp;
    }
    const int offs0 = sa[t] - c0;                 // exclusive prefix
    const int offs1 = sa[t + 256] - c1;
    if (blockIdx.x == 0) { wsi[WS_OFFS + t] = offs0; wsi[WS_OFFS + t + 256] = offs1; }

    int* hist = sb;                               // free buffer after scan
    hist[t] = 0; hist[t + 256] = 0;
    lc[t] = 0;  lc[t + 256] = 0;
    __syncthreads();
#pragma unroll
    for (int j = 0; j < SCT / 256; ++j) {
        const int k = (int)out[OFF_IDX + base + j * 256 + t];
        codes[j * 256 + t] = k;
        atomicAdd(&hist[k], 1);
    }
    __syncthreads();
    const int ha = hist[t];
    const int hb = hist[t + 256];
    int ga = 0, gb = 0;
    if (ha > 0) ga = atomicAdd(&wsi[WS_CUR + t], ha);
    if (hb > 0) gb = atomicAdd(&wsi[WS_CUR + t + 256], hb);
    __syncthreads();
    hist[t] = offs0 + ga;                         // absolute base per code
    hist[t + 256] = offs1 + gb;
    __syncthreads();
#pragma unroll
    for (int j = 0; j < SCT / 256; ++j) {
        const int k = codes[j * 256 + t];
        const int pos = atomicAdd(&lc[k], 1);
        wsi[WS_SORT + hist[k] + pos] = base + j * 256 + t;
    }
}

// ---------------------------------------------------------------------------
// K4: dw partials (depth-8 gathers — R9-proven config).
// ---------------------------------------------------------------------------
__global__ __launch_bounds__(64) void k_dw_split(float* __restrict__ out,
                                                 float* __restrict__ wsf,
                                                 const int* __restrict__ wsi) {
    const int lane = threadIdx.x;
    const int k = blockIdx.x >> 3;
    const int p = blockIdx.x & (SPLITS - 1);
    const int off = wsi[WS_OFFS + k];
    const int cnt = wsi[WS_CNT + k];
    const int chunk = (cnt + SPLITS - 1) >> 3;
    const int j0 = p * chunk;
    const int j1 = min(j0 + chunk, cnt);
    const float* fx = out + OFF_Q;
    const int* sort = wsi + WS_SORT + off;

    float acc = 0.f;
    for (int base = j0; base < j1; base += 64) {
        const int mcnt = min(64, j1 - base);
        int id = 0;
        if (base + lane < j1) id = sort[base + lane];
        int m = 0;
        for (; m + 8 <= mcnt; m += 8) {
            const int t0 = __shfl(id, m + 0, 64);
            const int t1 = __shfl(id, m + 1, 64);
            const int t2 = __shfl(id, m + 2, 64);
            const int t3 = __shfl(id, m + 3, 64);
            const int t4 = __shfl(id, m + 4, 64);
            const int t5 = __shfl(id, m + 5, 64);
            const int t6 = __shfl(id, m + 6, 64);
            const int t7 = __shfl(id, m + 7, 64);
            const float v0 = fx[(size_t)t0 * C_ + lane];
            const float v1 = fx[(size_t)t1 * C_ + lane];
            const float v2 = fx[(size_t)t2 * C_ + lane];
            const float v3 = fx[(size_t)t3 * C_ + lane];
            const float v4 = fx[(size_t)t4 * C_ + lane];
            const float v5 = fx[(size_t)t5 * C_ + lane];
            const float v6 = fx[(size_t)t6 * C_ + lane];
            const float v7 = fx[(size_t)t7 * C_ + lane];
            acc += ((v0 + v1) + (v2 + v3)) + ((v4 + v5) + (v6 + v7));
        }
        for (; m < mcnt; ++m) {
            const int tk = __shfl(id, m, 64);
            acc += fx[(size_t)tk * C_ + lane];
        }
    }
    wsf[WS_PART + (size_t)blockIdx.x * C_ + lane] = acc;
}

// ---------------------------------------------------------------------------
// K5: fused stats + ema + quant (R9-proven config).
// ---------------------------------------------------------------------------
__global__ __launch_bounds__(256) void k_emaq(const float* __restrict__ embed,
                                              const float* __restrict__ embed_avg,
                                              const float* __restrict__ cs,
                                              float* __restrict__ out,
                                              const float* __restrict__ wsf,
                                              const int* __restrict__ wsi) {
    __shared__ float sn[256];
    __shared__ float sncs[K_];
    const int t = threadIdx.x;
    const int bid = blockIdx.x;

    const int c0 = wsi[WS_CNT + t];
    const int c1 = wsi[WS_CNT + t + 256];
    const float ncs0 = cs[t] * DECAY_ + ONEM_ * (float)c0;
    const float ncs1 = cs[t + 256] * DECAY_ + ONEM_ * (float)c1;
    sncs[t] = ncs0; sncs[t + 256] = ncs1;
    sn[t] = ncs0 + ncs1;
    __syncthreads();
    for (int o = 128; o > 0; o >>= 1) { if (t < o) sn[t] += sn[t + o]; __syncthreads(); }
    const float ntot = sn[0];
    __syncthreads();

    if (bid == 0) {
        out[OFF_NCS + t] = ncs0;
        out[OFF_NCS + t + 256] = ncs1;
        const float ap0 = (float)c0 / (float)N_;
        const float ap1 = (float)c1 / (float)N_;
        sn[t] = ap0 * logf(ap0 + 1e-10f) + ap1 * logf(ap1 + 1e-10f);
        __syncthreads();
        for (int o = 128; o > 0; o >>= 1) { if (t < o) sn[t] += sn[t + o]; __syncthreads(); }
        if (t == 0) {
            out[OFF_PERP] = expf(-sn[0]);
            out[OFF_LOSS] = 0.25f * wsf[WS_LOSS] / (float)((long long)N_ * C_);
        }
    }

    if (bid < 128) {
        const int i = bid * 256 + t;           // i = k*64 + c
        const int k = i >> 6;
        const int c = i & 63;
        const float smooth = ntot * (sncs[k] + ALPHA_) / (ntot + (float)K_ * ALPHA_);
        float dw = 0.f;
#pragma unroll
        for (int p = 0; p < SPLITS; ++p)
            dw += wsf[WS_PART + (size_t)(k * SPLITS + p) * C_ + c];
        const float nea = embed_avg[i] * DECAY_ + ONEM_ * dw;
        out[OFF_NEA + i] = nea;
        out[OFF_NEMB + i] = nea / smooth;
    }

    const int n = bid * 256 + t;
    const int b = n >> 15;
    const int s = n & (S_ - 1);
    const int qbase = (b << 21) + s;
    const int k = (int)out[OFF_IDX + n];
    const float4* er = (const float4*)(embed + k * C_);
#pragma unroll
    for (int q = 0; q < 16; ++q) {
        float4 v = er[q];
        out[OFF_Q + qbase + ((4 * q + 0) << 15)] = v.x;
        out[OFF_Q + qbase + ((4 * q + 1) << 15)] = v.y;
        out[OFF_Q + qbase + ((4 * q + 2) << 15)] = v.z;
        out[OFF_Q + qbase + ((4 * q + 3) << 15)] = v.w;
    }
}

extern "C" void kernel_launch(void* const* d_in, const int* in_sizes, int n_in,
                              void* d_out, int out_size, void* d_ws, size_t ws_size,
                              hipStream_t stream) {
    const float* in        = (const float*)d_in[0];
    const float* embed     = (const float*)d_in[1];
    const float* embed_avg = (const float*)d_in[2];
    const float* cs        = (const float*)d_in[3];
    float* out = (float*)d_out;
    float* wsf = (float*)d_ws;
    int*   wsi = (int*)d_ws;

    k_split   <<<K_ / 4, 256, 0, stream>>>(embed, wsf, wsi);
    k_assign  <<<N_ / 256, 256, 0, stream>>>(in, out, wsf, wsi);
    k_fixup   <<<256, 256, 0, stream>>>(out, wsf, wsi);
    k_scatter <<<N_ / SCT, 256, 0, stream>>>(out, wsi);
    k_dw_split<<<K_ * SPLITS, 64, 0, stream>>>(out, wsf, wsi);
    k_emaq    <<<N_ / 256, 256, 0, stream>>>(embed, embed_avg, cs, out, wsf, wsi);
}